// Round 3
// baseline (2394.060 us; speedup 1.0000x reference)
//
#include <hip/hip_runtime.h>
#include <math.h>

#define BB 2
#define HH 16
#define SS 2048
#define DD 64
#define TQ 8            // q rows per block
#define CHUNK 256       // score columns per chunk
#define NCHUNK (SS / CHUNK)
#define CSTR 264        // chunk row stride (f32): 264 % 32 == 8 -> row r starts bank 8r

typedef __attribute__((ext_vector_type(8))) short bf16x8;
typedef __attribute__((ext_vector_type(4))) float f32x4;
typedef __attribute__((ext_vector_type(4))) int i32x4;

__device__ __forceinline__ unsigned short f2bf(float f) {
    unsigned u = __float_as_uint(f);
    u += 0x7FFF + ((u >> 16) & 1);   // RNE
    return (unsigned short)(u >> 16);
}
__device__ __forceinline__ float bf2f(unsigned short h) {
    return __uint_as_float(((unsigned)h) << 16);
}

// Pack 2 f32 -> 2 bf16 (hi parts) + 2 bf16 (lo residuals), packed u32 each.
__device__ __forceinline__ void split2(float x0, float x1,
                                       unsigned &hp, unsigned &lp) {
    asm("v_cvt_pk_bf16_f32 %0, %1, %2" : "=v"(hp) : "v"(x0), "v"(x1));
    const float h0 = __uint_as_float(hp << 16);
    const float h1 = __uint_as_float(hp & 0xffff0000u);
    const float l0 = x0 - h0;
    const float l1 = x1 - h1;
    asm("v_cvt_pk_bf16_f32 %0, %1, %2" : "=v"(lp) : "v"(l0), "v"(l1));
}

// Exact integer-threshold T5 bucket (bidirectional, 32 buckets, max_distance=128).
__device__ __forceinline__ int rel_bucket(int cpq, int mpk) {
    int n = cpq - mpk;
    int ret = 0;
    if (n < 0) { ret = 16; n = -n; }
    int v;
    if (n < 8) v = n;
    else {
        int j = (n >= 12) + (n >= 16) + (n >= 23) + (n >= 32) +
                (n >= 46) + (n >= 64) + (n >= 91);
        v = 8 + j;
    }
    return ret + v;
}

// Pre-kernel 1: K f32 -> bf16 once.
__launch_bounds__(256)
__global__ void conv_k_bf16(const float* __restrict__ src,
                            unsigned short* __restrict__ dst) {
    const size_t i = ((size_t)blockIdx.x * 256 + threadIdx.x) * 8;
    float4 f0 = *(const float4*)(src + i);
    float4 f1 = *(const float4*)(src + i + 4);
    union { bf16x8 v; unsigned short u[8]; } o;
    o.u[0] = f2bf(f0.x); o.u[1] = f2bf(f0.y); o.u[2] = f2bf(f0.z); o.u[3] = f2bf(f0.w);
    o.u[4] = f2bf(f1.x); o.u[5] = f2bf(f1.y); o.u[6] = f2bf(f1.z); o.u[7] = f2bf(f1.w);
    *(bf16x8*)(dst + i) = o.v;
}

// Pre-kernel 2: V -> transposed split-bf16 planes vt_hi/vt_lo [bh][d][c].
__launch_bounds__(256)
__global__ void conv_v_t(const float* __restrict__ v,
                         unsigned short* __restrict__ vt_hi,
                         unsigned short* __restrict__ vt_lo) {
    __shared__ float tile[64][65];
    const int bh = blockIdx.x >> 5;
    const int ct = blockIdx.x & 31;
    const int c0 = ct * 64;
    const float* vb = v + ((size_t)bh * SS + c0) * DD;
    const int tid = threadIdx.x;
    #pragma unroll
    for (int it = 0; it < 16; ++it) {
        const int idx = it * 256 + tid;
        tile[idx >> 6][idx & 63] = vb[idx];
    }
    __syncthreads();
    #pragma unroll
    for (int it = 0; it < 16; ++it) {
        const int idx = it * 256 + tid;
        const int d = idx >> 6, c = idx & 63;
        const float val = tile[c][d];
        const unsigned short hi = f2bf(val);
        const unsigned short lo = f2bf(val - bf2f(hi));
        const size_t o = ((size_t)bh * DD + d) * SS + c0 + c;
        vt_hi[o] = hi;
        vt_lo[o] = lo;
    }
}

__launch_bounds__(512, 8)   // 8 waves/EU => 4 blocks/CU (VGPR capped at 64)
__global__ void attn_tile_kernel(const float* __restrict__ qg,
                                 const unsigned short* __restrict__ kb,
                                 const unsigned short* __restrict__ vt_hi,
                                 const unsigned short* __restrict__ vt_lo,
                                 const float* __restrict__ bw,
                                 const int*   __restrict__ cp,
                                 const int*   __restrict__ mp,
                                 const int*   __restrict__ mask,
                                 float* __restrict__ o_out,
                                 float* __restrict__ a_out,
                                 float* __restrict__ p_out) {
    __shared__ __align__(16) float chunkbuf[2][TQ][CSTR];     // 16896 B, double-buffered
    __shared__ __align__(16) float partials[2 * TQ * DD];     // 4096 B (2 K-halves)
    __shared__ __align__(16) unsigned short q_lds[16 * 72];   // 2304 B
    __shared__ float bwh[32];
    // total ~23.4 KiB => LDS no longer caps occupancy; wave count does (4 blocks/CU)

    const int tid = threadIdx.x;
    // XCD-aware swizzle: 4 heads per XCD share K/V in L2.
    const int x   = blockIdx.x;
    const int xcd = x & 7;
    const int s_  = x >> 3;
    const int bh  = xcd * 4 + (s_ & 3);
    const int qt  = s_ >> 2;
    const int b   = bh >> 4;
    const int h   = bh & 15;
    const int q0  = qt * TQ;

    const unsigned short* Kbase = kb + (size_t)bh * SS * DD;

    // ---- stage Q tile (bf16, pre-scaled by 1/8 == exact pow2) + bias column ----
    {
        const float* Qrow = qg + ((size_t)bh * SS + q0) * DD;
        for (int e = tid; e < 16 * DD; e += 512) {
            int r = e >> 6, d = e & 63;
            q_lds[r * 72 + d] = (r < TQ) ? f2bf(Qrow[r * DD + d] * 0.125f)
                                         : (unsigned short)0;
        }
        if (tid < 32) bwh[tid] = bw[tid * HH + h];
    }
    __syncthreads();

    const int lane = tid & 63;
    const int wave = tid >> 6;
    const int quad = lane >> 4;
    const int l16  = lane & 15;

    // ---- softmax state (registers, per wave = one q-row) ----
    const int r  = wave;
    const int i  = lane;
    const int qi = q0 + r;
    const int cpq = cp[b * SS + qi];
    const int* mrow = mask + ((size_t)b * SS + qi) * SS;
    const int* mpb  = mp + b * SS;
    float* prow = p_out + ((size_t)bh * SS + qi) * SS;
    float sv[32];
    float mx = -3.0e38f;

    // ---- Fused A+B loop: per 256-col chunk {QK^T MFMA -> LDS; bias+mask+max} ----
    for (int c = 0; c < NCHUNK; ++c) {
        // Phase A-chunk: each wave computes 2 key-tiles of 16 (cols c*256 + wave*32..)
        {
            bf16x8 a0 = *(const bf16x8*)&q_lds[l16 * 72 + quad * 8];       // q dims 0..31
            bf16x8 a1 = *(const bf16x8*)&q_lds[l16 * 72 + 32 + quad * 8];  // q dims 32..63
            #pragma unroll
            for (int t = 0; t < 2; ++t) {
                const int ktl = wave * 2 + t;            // local key tile 0..15
                const int kt  = c * 16 + ktl;
                const unsigned short* kp = Kbase + (size_t)(kt * 16 + l16) * DD + quad * 8;
                bf16x8 b0 = *(const bf16x8*)(kp);
                bf16x8 b1 = *(const bf16x8*)(kp + 32);
                f32x4 acc = {0.f, 0.f, 0.f, 0.f};
                acc = __builtin_amdgcn_mfma_f32_16x16x32_bf16(a0, b0, acc, 0, 0, 0);
                acc = __builtin_amdgcn_mfma_f32_16x16x32_bf16(a1, b1, acc, 0, 0, 0);
                // C: row=(lane>>4)*4+reg, col=lane&15; rows >= TQ discarded
                if (quad < 2) {
                    const int col = ktl * 16 + l16;
                    const int rb  = quad * 4;
                    chunkbuf[c & 1][rb + 0][col] = acc[0];
                    chunkbuf[c & 1][rb + 1][col] = acc[1];
                    chunkbuf[c & 1][rb + 2][col] = acc[2];
                    chunkbuf[c & 1][rb + 3][col] = acc[3];
                }
            }
        }
        __syncthreads();   // single barrier/iter: double buffer covers WAR to c+2
        // Phase B-chunk: wave r consumes row r of the chunk (4 elems/lane)
        {
            const int cg = c * CHUNK + i * 4;
            i32x4 m4  = *(const i32x4*)(mrow + cg);
            i32x4 mp4 = *(const i32x4*)(mpb + cg);
            f32x4 s4  = *(const f32x4*)&chunkbuf[c & 1][r][i * 4];
            f32x4 p4;
            #pragma unroll
            for (int u = 0; u < 4; ++u) {
                p4[u] = bwh[rel_bucket(cpq, mp4[u])];
                float s = s4[u] + p4[u];
                if (m4[u] != 0) s = -1.0e9f;
                sv[c * 4 + u] = s;
                mx = fmaxf(mx, s);
            }
            *(f32x4*)(prow + cg) = p4;
        }
    }

    // ---- row max, exp, sum, write normalized a_out from registers ----
    {
        #pragma unroll
        for (int off = 32; off >= 1; off >>= 1)
            mx = fmaxf(mx, __shfl_xor(mx, off));
        float sum = 0.f;
        #pragma unroll
        for (int j = 0; j < 32; ++j) {
            sv[j] = __expf(sv[j] - mx);
            sum += sv[j];
        }
        #pragma unroll
        for (int off = 32; off >= 1; off >>= 1)
            sum += __shfl_xor(sum, off);
        const float inv = 1.0f / sum;
        float* arow = a_out + ((size_t)bh * SS + qi) * SS;
        #pragma unroll
        for (int c = 0; c < NCHUNK; ++c) {
            const int cg = c * CHUNK + i * 4;
            f32x4 o4;
            #pragma unroll
            for (int u = 0; u < 4; ++u) o4[u] = sv[c * 4 + u] * inv;
            *(f32x4*)(arow + cg) = o4;
        }
    }
    __syncthreads();   // vmcnt(0) drain: a_out visible (L2) to all waves; no prior
                       // L1 copies of a_out exist in this block -> reads are clean

    // ---- Phase E: PV = A·V via split-bf16 MFMA, A read back from a_out (L2-hot).
    // o[r][d] = sum_c a[r][c]·v[c][d]; a,v split hi+lo; lo·lo dropped (~2^-18).
    {
        const int kc = wave >> 2;            // K half
        const int d0 = (wave & 3) * 16;      // d tile
        const float* aB = a_out + ((size_t)bh * SS + q0 + (l16 & 7)) * SS + quad * 8;
        const unsigned short* vhiB = vt_hi + ((size_t)bh * DD + d0 + l16) * SS + quad * 8;
        const unsigned short* vloB = vt_lo + ((size_t)bh * DD + d0 + l16) * SS + quad * 8;
        f32x4 acc1 = {0.f, 0.f, 0.f, 0.f};   // ah*vh
        f32x4 acc2 = {0.f, 0.f, 0.f, 0.f};   // al*vh
        f32x4 acc3 = {0.f, 0.f, 0.f, 0.f};   // ah*vl
        #pragma unroll 2
        for (int s = 0; s < 32; ++s) {
            const int k0 = kc * 1024 + s * 32;
            f32x4 x0 = *(const f32x4*)(aB + k0);
            f32x4 x1 = *(const f32x4*)(aB + k0 + 4);
            union { bf16x8 v; unsigned u[4]; } ah, al;
            split2(x0[0], x0[1], ah.u[0], al.u[0]);
            split2(x0[2], x0[3], ah.u[1], al.u[1]);
            split2(x1[0], x1[1], ah.u[2], al.u[2]);
            split2(x1[2], x1[3], ah.u[3], al.u[3]);
            bf16x8 bhi = *(const bf16x8*)(vhiB + k0);
            bf16x8 blo = *(const bf16x8*)(vloB + k0);
            acc1 = __builtin_amdgcn_mfma_f32_16x16x32_bf16(ah.v, bhi, acc1, 0, 0, 0);
            acc2 = __builtin_amdgcn_mfma_f32_16x16x32_bf16(al.v, bhi, acc2, 0, 0, 0);
            acc3 = __builtin_amdgcn_mfma_f32_16x16x32_bf16(ah.v, blo, acc3, 0, 0, 0);
        }
        if (quad < 2) {                       // keep C rows 0..7 only
            #pragma unroll
            for (int rg = 0; rg < 4; ++rg) {
                const int row = quad * 4 + rg;
                partials[kc * (TQ * DD) + row * DD + d0 + l16] =
                    acc1[rg] + acc2[rg] + acc3[rg];
            }
        }
    }
    __syncthreads();

    // ---- reduce over 2 K-halves, write out (A already normalized) ----
    {
        const int rr = tid >> 6;              // 512 threads = TQ*DD elems
        const float v = partials[tid] + partials[512 + tid];
        o_out[((size_t)bh * SS + q0 + rr) * DD + (tid & 63)] = v;
    }
}

extern "C" void kernel_launch(void* const* d_in, const int* in_sizes, int n_in,
                              void* d_out, int out_size, void* d_ws, size_t ws_size,
                              hipStream_t stream) {
    const float* q  = (const float*)d_in[0];
    const float* k  = (const float*)d_in[1];
    const float* v  = (const float*)d_in[2];
    const float* bw = (const float*)d_in[3];
    const int*   cp = (const int*)d_in[4];
    const int*   mp = (const int*)d_in[5];
    const int*   mask = (const int*)d_in[6];

    float* o_out = (float*)d_out;                                   // [B,H,S,D]
    float* a_out = o_out + (size_t)BB * HH * SS * DD;               // [B,H,S,S]
    float* p_out = a_out + (size_t)BB * HH * SS * SS;               // [B,H,S,S]

    // workspace: K bf16 + V^T hi plane + V^T lo plane (3 x 8.4 MB)
    const size_t NE = (size_t)BB * HH * SS * DD;
    unsigned short* kb    = (unsigned short*)d_ws;
    unsigned short* vt_hi = kb + NE;
    unsigned short* vt_lo = kb + 2 * NE;

    const int conv_grid = (int)(NE / (8 * 256));
    conv_k_bf16<<<conv_grid, 256, 0, stream>>>(k, kb);
    conv_v_t<<<BB * HH * (SS / 64), 256, 0, stream>>>(v, vt_hi, vt_lo);

    const int grid = BB * HH * (SS / TQ);            // 8192 blocks
    attn_tile_kernel<<<grid, 512, 0, stream>>>(q, kb, vt_hi, vt_lo, bw, cp, mp, mask,
                                               o_out, a_out, p_out);
}